// Round 8
// baseline (106.269 us; speedup 1.0000x reference)
//
#include <hip/hip_runtime.h>
#include <hip/hip_bf16.h>

// Problem constants (fixed-shape problem)
#define KNB    32
#define DEMB   128
#define HIDN   100
#define OUTU   20
#define HHEADS 5
#define OUTW   228   // H*OUT + D = 100 + 128

#define NWAVES 8     // waves per block
#define NPAIR  5     // pairs per wave -> 10 nodes/wave, 80 nodes/block, grid 250

typedef __attribute__((ext_vector_type(4))) float f32x4;
typedef __attribute__((ext_vector_type(8))) short bf16x8;

__device__ __forceinline__ unsigned short f2bf(float f) {
    union { float f; unsigned u; } v; v.f = f;
    unsigned r = (v.u + 0x7fffu + ((v.u >> 16) & 1u)) >> 16;
    return (unsigned short)r;
}
__device__ __forceinline__ unsigned pkbf(float lo, float hi) {
    unsigned r;
    asm("v_cvt_pk_bf16_f32 %0, %1, %2" : "=v"(r) : "v"(lo), "v"(hi));
    return r;
}
__device__ __forceinline__ bf16x8 cvt8(float4 a, float4 b) {
    union { unsigned u[4]; bf16x8 v; } t;
    t.u[0] = pkbf(a.x, a.y); t.u[1] = pkbf(a.z, a.w);
    t.u[2] = pkbf(b.x, b.y); t.u[3] = pkbf(b.z, b.w);
    return t.v;
}

// ---------------- prep: FRAGMENT-MAJOR weight layouts (unchanged from R4) ----------------
__global__ void sa_prep(const float* __restrict__ W1, const float* __restrict__ W2,
                        unsigned short* __restrict__ W1f, unsigned short* __restrict__ W2f) {
    int idx = blockIdx.x * 256 + threadIdx.x;          // 32768 total
    if (idx < 28672) {
        int e = idx & 7, lane = (idx >> 3) & 63, ks = (idx >> 9) & 7, jt = idx >> 12;
        int j = jt * 16 + (lane & 15);
        int d = ks * 32 + (lane >> 4) * 8 + e;
        W1f[idx] = (j < HIDN) ? f2bf(W1[d * HIDN + j]) : (unsigned short)0;
    } else {
        int i2 = idx - 28672;                          // < 4096
        int e = i2 & 7, lane = (i2 >> 3) & 63, ot = (i2 >> 9) & 1, ks = i2 >> 10;
        int o = ot * 16 + (lane & 15);
        int jj = ks * 32 + (lane >> 4) * 8 + e;
        W2f[i2] = (o < OUTU && jj < HIDN) ? f2bf(W2[jj * OUTU + o]) : (unsigned short)0;
    }
}

// prefetch state for one node: 24 float4, all statically indexed (registers, no scratch)
struct Gath { float4 a[4], c[4], d[4], e[4], f[4], g[4]; };

__device__ __forceinline__ int issue_node(Gath& G, const float* __restrict__ emb,
        const int* __restrict__ neigh_idx, const int* __restrict__ node_idx,
        int node, int l15, int h4) {
    const int* nip = neigh_idx + (size_t)node * KNB;
    int r0 = nip[l15], r1 = nip[16 + l15];
    int nid = node_idx[node];
    const float* p0 = emb + (size_t)r0 * DEMB + h4 * 8;
    const float* p1 = emb + (size_t)r1 * DEMB + h4 * 8;
    const float* pn = emb + (size_t)nid * DEMB + h4 * 8;
#pragma unroll
    for (int ks = 0; ks < 4; ++ks) {
        G.a[ks] = *(const float4*)(p0 + ks * 32); G.c[ks] = *(const float4*)(p0 + ks * 32 + 4);
        G.d[ks] = *(const float4*)(p1 + ks * 32); G.e[ks] = *(const float4*)(p1 + ks * 32 + 4);
        G.f[ks] = *(const float4*)(pn + ks * 32); G.g[ks] = *(const float4*)(pn + ks * 32 + 4);
    }
    return nid;
}

__device__ __forceinline__ void cvt_node(const Gath& G, bf16x8 b0[4], bf16x8 b1f[4], bf16x8 bn[4]) {
#pragma unroll
    for (int ks = 0; ks < 4; ++ks) {
        b0[ks]  = cvt8(G.a[ks], G.c[ks]);
        b1f[ks] = cvt8(G.d[ks], G.e[ks]);
        bn[ks]  = cvt8(G.f[ks], G.g[ks]);
    }
}

// fused GEMM1->GEMM2 for ONE node (K-sliced through stg)
__device__ __forceinline__ void gemm_node(const bf16x8* __restrict__ w1f_v,
        const bf16x8* __restrict__ w2f_v, char* stg, const float* __restrict__ bias1,
        const bf16x8 b0[4], const bf16x8 b1f[4], const bf16x8 bn[4],
        f32x4 acc[2][2], int lane, int l15, int h4) {
#pragma unroll
    for (int ks = 0; ks < 4; ++ks) {
#pragma unroll
        for (int jt2 = 0; jt2 < 2; ++jt2) {
            const int jt = ks * 2 + jt2;
            const int co = jt2 * 32 + h4 * 8;
            if (jt < 7) {
                f32x4 a0 = {0.f, 0.f, 0.f, 0.f}, a1 = {0.f, 0.f, 0.f, 0.f};
#pragma unroll
                for (int kk = 0; kk < 8; ++kk) {
                    bf16x8 afr = w1f_v[(jt * 8 + kk) * 64 + lane];
                    bf16x8 u0 = (kk < 4) ? b0[kk & 3]  : bn[kk & 3];
                    bf16x8 u1 = (kk < 4) ? b1f[kk & 3] : bn[kk & 3];
                    a0 = __builtin_amdgcn_mfma_f32_16x16x32_bf16(afr, u0, a0, 0, 0, 0);
                    a1 = __builtin_amdgcn_mfma_f32_16x16x32_bf16(afr, u1, a1, 0, 0, 0);
                }
                const int j0 = jt * 16 + h4 * 4;
                float4 bv;
                if (j0 + 3 < HIDN) bv = *(const float4*)(bias1 + j0);
                else bv = make_float4(0.f, 0.f, 0.f, 0.f);   // j>=100: acc is 0 there too
                *(uint2*)(stg + l15 * 80 + co) =
                    make_uint2(pkbf(fmaxf(a0[0] + bv.x, 0.f), fmaxf(a0[1] + bv.y, 0.f)),
                               pkbf(fmaxf(a0[2] + bv.z, 0.f), fmaxf(a0[3] + bv.w, 0.f)));
                *(uint2*)(stg + (16 + l15) * 80 + co) =
                    make_uint2(pkbf(fmaxf(a1[0] + bv.x, 0.f), fmaxf(a1[1] + bv.y, 0.f)),
                               pkbf(fmaxf(a1[2] + bv.z, 0.f), fmaxf(a1[3] + bv.w, 0.f)));
            } else {
                *(uint2*)(stg + l15 * 80 + co)        = make_uint2(0u, 0u);
                *(uint2*)(stg + (16 + l15) * 80 + co) = make_uint2(0u, 0u);
            }
        }
        // GEMM2 K-step ks
        bf16x8 af0 = *(const bf16x8*)(stg + l15 * 80 + h4 * 16);
        bf16x8 af1 = *(const bf16x8*)(stg + (16 + l15) * 80 + h4 * 16);
        bf16x8 w20 = w2f_v[(ks * 2 + 0) * 64 + lane];
        bf16x8 w21 = w2f_v[(ks * 2 + 1) * 64 + lane];
        acc[0][0] = __builtin_amdgcn_mfma_f32_16x16x32_bf16(af0, w20, acc[0][0], 0, 0, 0);
        acc[0][1] = __builtin_amdgcn_mfma_f32_16x16x32_bf16(af0, w21, acc[0][1], 0, 0, 0);
        acc[1][0] = __builtin_amdgcn_mfma_f32_16x16x32_bf16(af1, w20, acc[1][0], 0, 0, 0);
        acc[1][1] = __builtin_amdgcn_mfma_f32_16x16x32_bf16(af1, w21, acc[1][1], 0, 0, 0);
    }
}

// ---------------- main: 8 waves, 10 nodes/wave, a/b-staggered cross-node prefetch ----------------
// LDS: 57344 (W1f) + 8192 (W2f) + 8*9600 (per-wave stg + 2x{tT,pf}) = 142336 B -> 1 block/CU.
__global__ __launch_bounds__(NWAVES * 64, 2)   // 2 waves/EU -> 256 VGPR budget for the pipeline
void sa_main(const float* __restrict__ emb,
             const int* __restrict__ node_idx,
             const int* __restrict__ neigh_idx,
             const float* __restrict__ b1,
             const float* __restrict__ b2,
             const float* __restrict__ Wa,
             const float* __restrict__ ba,
             const unsigned short* __restrict__ W1f,
             const unsigned short* __restrict__ W2f,
             float* __restrict__ out, int nnodes) {
    extern __shared__ char smem[];
    unsigned short* w1_lds = (unsigned short*)smem;                  // 57344 B
    unsigned short* w2_lds = (unsigned short*)(smem + 57344);        // 8192 B

    const int tid  = threadIdx.x;
    const int lane = tid & 63;
    const int wid  = tid >> 6;
    const int l15 = lane & 15, h4 = lane >> 4;
    const int nsel = lane >> 5, ln = lane & 31;      // half-wave node select for epilogue

    char* wbase = smem + 65536 + wid * 9600;
    char*  stg = wbase;                               // 32 rows x 80 B (shared a/b sequentially)
    float* tT0 = (float*)(wbase + 2560);              // 20*36*4 = 2880 B
    float* tT1 = (float*)(wbase + 5440);
    float* pf0 = (float*)(wbase + 8320);              // 160*4
    float* pf1 = (float*)(wbase + 8960);

    const bf16x8* w1f_v = (const bf16x8*)w1_lds;
    const bf16x8* w2f_v = (const bf16x8*)w2_lds;

    const int nbase = blockIdx.x * (NWAVES * 2 * NPAIR) + wid * (2 * NPAIR);
    const int nlast = nnodes - 1;

    // ---- weight staging loads FIRST (oldest in vmem queue -> ds_write waits only these) ----
    float4 st[7], st2;
#pragma unroll
    for (int i = 0; i < 7; ++i) st[i] = ((const float4*)W1f)[tid + i * 512];
    st2 = ((const float4*)W2f)[tid];

    // ---- prologue: issue pair-0 gathers ----
    Gath ga, gb;
    int na = nbase < nnodes ? nbase : nlast;
    int nb = nbase + 1 < nnodes ? nbase + 1 : nlast;
    int nida = issue_node(ga, emb, neigh_idx, node_idx, na, l15, h4);

    // weights to LDS (compiler waits vmcnt for st only; gathers keep flying)
#pragma unroll
    for (int i = 0; i < 7; ++i) ((float4*)w1_lds)[tid + i * 512] = st[i];
    ((float4*)w2_lds)[tid] = st2;

    int nidb = issue_node(gb, emb, neigh_idx, node_idx, nb, l15, h4);
    float4 ncp = ((const float4*)(emb + (size_t)(nsel ? nidb : nida) * DEMB))[ln];

    // raw barrier: only drain LDS writes, NOT the in-flight gathers
    asm volatile("s_waitcnt lgkmcnt(0)" ::: "memory");
    __builtin_amdgcn_s_barrier();
    __builtin_amdgcn_sched_barrier(0);

    for (int p = 0; p < NPAIR; ++p) {
        const int node_a = nbase + 2 * p;
        const int node_b = node_a + 1;

        // ---- node a: cvt (waits a-loads only) + GEMM ----
        bf16x8 f0[4], f1[4], fn[4];
        cvt_node(ga, f0, f1, fn);
        f32x4 acc_a[2][2] = {};
        gemm_node(w1f_v, w2f_v, stg, b1, f0, f1, fn, acc_a, lane, l15, h4);

        // ---- prefetch next-pair node a (hidden under GEMM b + epilogue) ----
        int na2 = node_a + 2 < nnodes ? node_a + 2 : nlast;
        int nida_n = issue_node(ga, emb, neigh_idx, node_idx, na2, l15, h4);
        __builtin_amdgcn_sched_barrier(0);

        // ---- node b: cvt + GEMM ----
        cvt_node(gb, f0, f1, fn);
        f32x4 acc_b[2][2] = {};
        gemm_node(w1f_v, w2f_v, stg, b1, f0, f1, fn, acc_b, lane, l15, h4);

        // ---- epilogue for the pair (half-wave per node) ----
        {
            const int node_h = nsel ? node_b : node_a;
#pragma unroll
            for (int ot = 0; ot < 2; ++ot) {
                int o = ot * 16 + l15;
                if (o < OUTU) {
                    float b2v = b2[o];
#pragma unroll
                    for (int mt = 0; mt < 2; ++mt) {
                        int m0 = mt * 16 + h4 * 4;
                        f32x4 va = acc_a[mt][ot];
                        *(float4*)&tT0[o * 36 + m0] =
                            make_float4(fmaxf(va[0] + b2v, 0.f), fmaxf(va[1] + b2v, 0.f),
                                        fmaxf(va[2] + b2v, 0.f), fmaxf(va[3] + b2v, 0.f));
                        f32x4 vb = acc_b[mt][ot];
                        *(float4*)&tT1[o * 36 + m0] =
                            make_float4(fmaxf(vb[0] + b2v, 0.f), fmaxf(vb[1] + b2v, 0.f),
                                        fmaxf(vb[2] + b2v, 0.f), fmaxf(vb[3] + b2v, 0.f));
                    }
                }
            }
            float* tT_h = nsel ? tT1 : tT0;
            float* pf_h = nsel ? pf1 : pf0;

            if (node_h < nnodes)
                ((float4*)(out + (size_t)node_h * OUTW + HHEADS * OUTU))[ln] = ncp;

            float tv[20];
#pragma unroll
            for (int o = 0; o < OUTU; ++o) tv[o] = tT_h[o * 36 + ln];
            float att[5];
#pragma unroll
            for (int h = 0; h < HHEADS; ++h) {
                float s = ba[h];
#pragma unroll
                for (int o = 0; o < OUTU; ++o) s += tv[o] * Wa[o * HHEADS + h];
                att[h] = fmaxf(s, 0.f);
            }
            float mx = att[0];
#pragma unroll
            for (int h = 1; h < HHEADS; ++h) mx = fmaxf(mx, att[h]);
            float e[5], sum = 0.f;
#pragma unroll
            for (int h = 0; h < HHEADS; ++h) { e[h] = __expf(att[h] - mx); sum += e[h]; }
            float inv = 1.f / sum;
#pragma unroll
            for (int h = 0; h < HHEADS; ++h) pf_h[ln * HHEADS + h] = e[h] * inv;

#pragma unroll
            for (int pass = 0; pass < 4; ++pass) {
                int idx = pass * 32 + ln;
                if (idx < HHEADS * OUTU && node_h < nnodes) {
                    int h = idx / OUTU, o = idx % OUTU;
                    float s = 0.f;
#pragma unroll
                    for (int kk = 0; kk < 8; ++kk) {
                        float4 p4 = *(const float4*)&pf_h[h * 32 + kk * 4];
                        float4 t4 = *(const float4*)&tT_h[o * 36 + kk * 4];
                        s += p4.x * t4.x + p4.y * t4.y + p4.z * t4.z + p4.w * t4.w;
                    }
                    out[(size_t)node_h * OUTW + idx] = s;
                }
            }
        }

        // ---- prefetch next-pair node b + next pair's node-row copy ----
        int nb2 = node_b + 2 < nnodes ? node_b + 2 : nlast;
        int nidb_n = issue_node(gb, emb, neigh_idx, node_idx, nb2, l15, h4);
        nida = nida_n; nidb = nidb_n;
        ncp = ((const float4*)(emb + (size_t)(nsel ? nidb : nida) * DEMB))[ln];
        __builtin_amdgcn_sched_barrier(0);
    }
}

extern "C" void kernel_launch(void* const* d_in, const int* in_sizes, int n_in,
                              void* d_out, int out_size, void* d_ws, size_t ws_size,
                              hipStream_t stream) {
    const float* emb      = (const float*)d_in[0];
    const int*   node_idx = (const int*)d_in[1];
    const int*   neigh_idx= (const int*)d_in[2];
    const float* W1       = (const float*)d_in[3];
    const float* b1       = (const float*)d_in[4];
    const float* W2       = (const float*)d_in[5];
    const float* b2       = (const float*)d_in[6];
    const float* Wa       = (const float*)d_in[7];
    const float* ba       = (const float*)d_in[8];
    float* out = (float*)d_out;

    unsigned short* W1f = (unsigned short*)d_ws;            // 28672 bf16 = 57344 B (frag-major)
    unsigned short* W2f = W1f + 28672;                      // 4096 bf16  =  8192 B (contiguous)

    int n = in_sizes[1];                                    // 20000 nodes
    int smem_bytes = 57344 + 8192 + NWAVES * 9600;          // 142336 B

    static bool attr_set = false;   // idempotent driver attr; not a stream op (graph-safe)
    if (!attr_set) {
        hipFuncSetAttribute((const void*)sa_main,
                            hipFuncAttributeMaxDynamicSharedMemorySize, smem_bytes);
        attr_set = true;
    }

    sa_prep<<<128, 256, 0, stream>>>(W1, W2, W1f, W2f);
    int npb = NWAVES * 2 * NPAIR;                           // 80 nodes per block
    sa_main<<<(n + npb - 1) / npb, NWAVES * 64, smem_bytes, stream>>>(
        emb, node_idx, neigh_idx, b1, b2, Wa, ba, W1f, W2f, out, n);
}

// Round 9
// 103.527 us; speedup vs baseline: 1.0265x; 1.0265x over previous
//
#include <hip/hip_runtime.h>
#include <hip/hip_bf16.h>

// Problem constants (fixed-shape problem)
#define KNB    32
#define DEMB   128
#define HIDN   100
#define OUTU   20
#define HHEADS 5
#define OUTW   228   // H*OUT + D = 100 + 128

#define NITER  8     // nodes per wave in sa_main (grid 625 x 4 waves x 8 = 20000 exact)

typedef __attribute__((ext_vector_type(4))) float f32x4;
typedef __attribute__((ext_vector_type(8))) short bf16x8;

__device__ __forceinline__ unsigned short f2bf(float f) {
    union { float f; unsigned u; } v; v.f = f;
    unsigned r = (v.u + 0x7fffu + ((v.u >> 16) & 1u)) >> 16;
    return (unsigned short)r;
}
__device__ __forceinline__ unsigned pkbf(float lo, float hi) {
    unsigned r;
    asm("v_cvt_pk_bf16_f32 %0, %1, %2" : "=v"(r) : "v"(lo), "v"(hi));
    return r;
}
__device__ __forceinline__ bf16x8 cvt8(float4 a, float4 b) {
    union { unsigned u[4]; bf16x8 v; } t;
    t.u[0] = pkbf(a.x, a.y); t.u[1] = pkbf(a.z, a.w);
    t.u[2] = pkbf(b.x, b.y); t.u[3] = pkbf(b.z, b.w);
    return t.v;
}

// ---------------- prep: frag-major W1 halves + W2 ----------------
// W1fN[(jt*4+ks)*64+lane] elem e: W1[d][j], j=jt*16+(lane&15), d=ks*32+(lane>>4)*8+e   (d in [0,128))
// W1fM: same with d+128 (node half).  W2f[(ks*2+ot)*64+lane]: W2[j][o] frag-major.
__global__ void sa_prep(const float* __restrict__ W1, const float* __restrict__ W2,
                        unsigned short* __restrict__ W1fN, unsigned short* __restrict__ W1fM,
                        unsigned short* __restrict__ W2f) {
    int idx = blockIdx.x * 256 + threadIdx.x;          // 32768 total
    if (idx < 14336) {
        int e = idx & 7, lane = (idx >> 3) & 63, ks = (idx >> 9) & 3, jt = idx >> 11;
        int j = jt * 16 + (lane & 15);
        int d = ks * 32 + (lane >> 4) * 8 + e;
        W1fN[idx] = (j < HIDN) ? f2bf(W1[d * HIDN + j]) : (unsigned short)0;
    } else if (idx < 28672) {
        int i2 = idx - 14336;
        int e = i2 & 7, lane = (i2 >> 3) & 63, ks = (i2 >> 9) & 3, jt = i2 >> 11;
        int j = jt * 16 + (lane & 15);
        int d = ks * 32 + (lane >> 4) * 8 + e;
        W1fM[i2] = (j < HIDN) ? f2bf(W1[(128 + d) * HIDN + j]) : (unsigned short)0;
    } else {
        int i2 = idx - 28672;                          // < 4096
        int e = i2 & 7, lane = (i2 >> 3) & 63, ot = (i2 >> 9) & 1, ks = i2 >> 10;
        int o = ot * 16 + (lane & 15);
        int jj = ks * 32 + (lane >> 4) * 8 + e;
        W2f[i2] = (o < OUTU && jj < HIDN) ? f2bf(W2[jj * OUTU + o]) : (unsigned short)0;
    }
}

// ---------------- hproj: streaming GEMM, hproj[r][j] = sum_d emb[r][d]*W1[d][j], bf16 out ----------------
// 4 waves/block, 32 consecutive rows per wave. No LDS (W1fN frags hot in L2).
__global__ __launch_bounds__(256, 2)
void sa_hproj(const float* __restrict__ emb, const unsigned short* __restrict__ W1fN,
              unsigned short* __restrict__ hproj, int ntot) {
    const int tid = threadIdx.x, lane = tid & 63, wid = tid >> 6;
    const int l15 = lane & 15, h4 = lane >> 4;
    const int r0 = blockIdx.x * 128 + wid * 32 + l15;
    const int r1 = r0 + 16;
    const int r0c = r0 < ntot ? r0 : ntot - 1;
    const int r1c = r1 < ntot ? r1 : ntot - 1;
    const float* p0 = emb + (size_t)r0c * DEMB + h4 * 8;
    const float* p1 = emb + (size_t)r1c * DEMB + h4 * 8;
    const bf16x8* wv = (const bf16x8*)W1fN;

    f32x4 acc[7][2] = {};
#pragma unroll
    for (int ks = 0; ks < 4; ++ks) {
        bf16x8 b0 = cvt8(*(const float4*)(p0 + ks * 32), *(const float4*)(p0 + ks * 32 + 4));
        bf16x8 b1 = cvt8(*(const float4*)(p1 + ks * 32), *(const float4*)(p1 + ks * 32 + 4));
#pragma unroll
        for (int jt = 0; jt < 7; ++jt) {
            bf16x8 a = wv[(jt * 4 + ks) * 64 + lane];
            acc[jt][0] = __builtin_amdgcn_mfma_f32_16x16x32_bf16(a, b0, acc[jt][0], 0, 0, 0);
            acc[jt][1] = __builtin_amdgcn_mfma_f32_16x16x32_bf16(a, b1, acc[jt][1], 0, 0, 0);
        }
    }
    // store bf16, rows padded to 128 cols (j in [100,128) = 0 via zero W1fN rows / explicit zeros)
#pragma unroll
    for (int jt = 0; jt < 8; ++jt) {
        int j0 = jt * 16 + h4 * 4;
#pragma unroll
        for (int mt = 0; mt < 2; ++mt) {
            int r = mt ? r1 : r0;
            if (r < ntot) {
                uint2 v;
                if (jt < 7) {
                    f32x4 a = acc[jt][mt];
                    v = make_uint2(pkbf(a[0], a[1]), pkbf(a[2], a[3]));
                } else v = make_uint2(0u, 0u);
                *(uint2*)((char*)hproj + (size_t)r * 256 + j0 * 2) = v;
            }
        }
    }
}

// ---------------- nproj: nproj[n][j] = sum_d emb[node_idx[n]][128..256 half] * W1node + b1, f32 out ----------------
__global__ __launch_bounds__(256, 2)
void sa_nproj(const float* __restrict__ emb, const int* __restrict__ node_idx,
              const float* __restrict__ b1, const unsigned short* __restrict__ W1fM,
              float* __restrict__ nproj, int nn) {
    const int tid = threadIdx.x, lane = tid & 63, wid = tid >> 6;
    const int l15 = lane & 15, h4 = lane >> 4;
    const int n0 = blockIdx.x * 128 + wid * 32 + l15;
    const int n1 = n0 + 16;
    const int n0c = n0 < nn ? n0 : nn - 1;
    const int n1c = n1 < nn ? n1 : nn - 1;
    const float* p0 = emb + (size_t)node_idx[n0c] * DEMB + h4 * 8;
    const float* p1 = emb + (size_t)node_idx[n1c] * DEMB + h4 * 8;
    const bf16x8* wv = (const bf16x8*)W1fM;

    f32x4 acc[7][2] = {};
#pragma unroll
    for (int ks = 0; ks < 4; ++ks) {
        bf16x8 b0 = cvt8(*(const float4*)(p0 + ks * 32), *(const float4*)(p0 + ks * 32 + 4));
        bf16x8 b1v = cvt8(*(const float4*)(p1 + ks * 32), *(const float4*)(p1 + ks * 32 + 4));
#pragma unroll
        for (int jt = 0; jt < 7; ++jt) {
            bf16x8 a = wv[(jt * 4 + ks) * 64 + lane];
            acc[jt][0] = __builtin_amdgcn_mfma_f32_16x16x32_bf16(a, b0, acc[jt][0], 0, 0, 0);
            acc[jt][1] = __builtin_amdgcn_mfma_f32_16x16x32_bf16(a, b1v, acc[jt][1], 0, 0, 0);
        }
    }
#pragma unroll
    for (int jt = 0; jt < 8; ++jt) {
        int j0 = jt * 16 + h4 * 4;
        float4 bv;
        if (jt < 7 && j0 + 3 < HIDN) bv = *(const float4*)(b1 + j0);
        else bv = make_float4(0.f, 0.f, 0.f, 0.f);
#pragma unroll
        for (int mt = 0; mt < 2; ++mt) {
            int n = mt ? n1 : n0;
            if (n < nn) {
                float4 v;
                if (jt < 7) {
                    f32x4 a = acc[jt][mt];
                    v = make_float4(a[0] + bv.x, a[1] + bv.y, a[2] + bv.z, a[3] + bv.w);
                } else v = make_float4(0.f, 0.f, 0.f, 0.f);
                *(float4*)(nproj + (size_t)n * 128 + j0) = v;
            }
        }
    }
}

// hid A-frag: relu(bf16(hproj) + f32(nproj)) -> packed bf16x8
__device__ __forceinline__ bf16x8 mkhid(uint4 hp, float4 na, float4 nb) {
    union { unsigned u[4]; bf16x8 v; } t;
    union { unsigned u; float f; } c0, c1;
    c0.u = hp.x << 16;          c1.u = hp.x & 0xffff0000u;
    t.u[0] = pkbf(fmaxf(c0.f + na.x, 0.f), fmaxf(c1.f + na.y, 0.f));
    c0.u = hp.y << 16;          c1.u = hp.y & 0xffff0000u;
    t.u[1] = pkbf(fmaxf(c0.f + na.z, 0.f), fmaxf(c1.f + na.w, 0.f));
    c0.u = hp.z << 16;          c1.u = hp.z & 0xffff0000u;
    t.u[2] = pkbf(fmaxf(c0.f + nb.x, 0.f), fmaxf(c1.f + nb.y, 0.f));
    c0.u = hp.w << 16;          c1.u = hp.w & 0xffff0000u;
    t.u[3] = pkbf(fmaxf(c0.f + nb.z, 0.f), fmaxf(c1.f + nb.w, 0.f));
    return t.v;
}

// ---------------- main: gather hproj rows (4 lines each) + GEMM2 + epilogue ----------------
// 4 waves/block, 1 node/wave/iter, NITER iters. LDS only 4x3520 B (epilogue). No barriers.
__global__ __launch_bounds__(256, 3)
void sa_main(const float* __restrict__ emb,
             const int* __restrict__ node_idx,
             const int* __restrict__ neigh_idx,
             const float* __restrict__ b2,
             const float* __restrict__ Wa,
             const float* __restrict__ ba,
             const unsigned short* __restrict__ hproj,
             const float* __restrict__ nproj,
             const unsigned short* __restrict__ W2f,
             float* __restrict__ out, int nnodes) {
    __shared__ char smem[4 * 3520];
    const int tid = threadIdx.x, lane = tid & 63, wid = tid >> 6;
    const int l15 = lane & 15, h4 = lane >> 4;

    char* wbase = smem + wid * 3520;
    float* tT_s = (float*)wbase;              // 20*36*4 = 2880 B
    float* pf_s = (float*)(wbase + 2880);     // 160*4   = 640 B

    // W2 fragments live in registers for the whole kernel (coalesced, L1-hot)
    bf16x8 w2r[4][2];
#pragma unroll
    for (int ks = 0; ks < 4; ++ks)
#pragma unroll
        for (int ot = 0; ot < 2; ++ot)
            w2r[ks][ot] = ((const bf16x8*)W2f)[(ks * 2 + ot) * 64 + lane];

    const int nbase = (blockIdx.x * 4 + wid) * NITER;

    for (int it = 0; it < NITER; ++it) {
        const int node = nbase + it;                 // grid exact: 625*4*8 = 20000
        if (node >= nnodes) return;
        const int* nip = neigh_idx + (size_t)node * KNB;
        const int m0 = nip[l15], m1 = nip[16 + l15];
        const int nid = node_idx[node];

        // ---- issue all gathers for this node ----
        const char* hp0 = (const char*)hproj + (size_t)m0 * 256 + h4 * 16;
        const char* hp1 = (const char*)hproj + (size_t)m1 * 256 + h4 * 16;
        const float* np = nproj + (size_t)node * 128 + h4 * 8;
        uint4 g0[4], g1[4]; float4 na[4], nb4[4];
#pragma unroll
        for (int ks = 0; ks < 4; ++ks) {
            g0[ks]  = *(const uint4*)(hp0 + ks * 64);
            g1[ks]  = *(const uint4*)(hp1 + ks * 64);
            na[ks]  = *(const float4*)(np + ks * 32);
            nb4[ks] = *(const float4*)(np + ks * 32 + 4);
        }
        float4 ncp;
        if (lane < 32) ncp = ((const float4*)(emb + (size_t)nid * DEMB))[lane];
        __builtin_amdgcn_sched_barrier(0);

        if (lane < 32)
            ((float4*)(out + (size_t)node * OUTW + HHEADS * OUTU))[lane] = ncp;

        // ---- GEMM2: hid built in-register from hproj+nproj ----
        f32x4 acc[2][2] = {};
#pragma unroll
        for (int ks = 0; ks < 4; ++ks) {
            bf16x8 a0 = mkhid(g0[ks], na[ks], nb4[ks]);
            bf16x8 a1 = mkhid(g1[ks], na[ks], nb4[ks]);
            acc[0][0] = __builtin_amdgcn_mfma_f32_16x16x32_bf16(a0, w2r[ks][0], acc[0][0], 0, 0, 0);
            acc[0][1] = __builtin_amdgcn_mfma_f32_16x16x32_bf16(a0, w2r[ks][1], acc[0][1], 0, 0, 0);
            acc[1][0] = __builtin_amdgcn_mfma_f32_16x16x32_bf16(a1, w2r[ks][0], acc[1][0], 0, 0, 0);
            acc[1][1] = __builtin_amdgcn_mfma_f32_16x16x32_bf16(a1, w2r[ks][1], acc[1][1], 0, 0, 0);
        }

        // ---- t = relu(D2 + b2), store transposed tT[o][m] ----
#pragma unroll
        for (int ot = 0; ot < 2; ++ot) {
            int o = ot * 16 + l15;
            if (o < OUTU) {
                float b2v = b2[o];
#pragma unroll
                for (int mt = 0; mt < 2; ++mt) {
                    int mm0 = mt * 16 + h4 * 4;
                    f32x4 a = acc[mt][ot];
                    *(float4*)&tT_s[o * 36 + mm0] =
                        make_float4(fmaxf(a[0] + b2v, 0.f), fmaxf(a[1] + b2v, 0.f),
                                    fmaxf(a[2] + b2v, 0.f), fmaxf(a[3] + b2v, 0.f));
                }
            }
        }

        // ---- attention + softmax over heads ----
        {
            int mm = lane & 31;
            float tv[20];
#pragma unroll
            for (int o = 0; o < OUTU; ++o) tv[o] = tT_s[o * 36 + mm];
            float att[5];
#pragma unroll
            for (int h = 0; h < HHEADS; ++h) {
                float s = ba[h];
#pragma unroll
                for (int o = 0; o < OUTU; ++o) s += tv[o] * Wa[o * HHEADS + h];
                att[h] = fmaxf(s, 0.f);
            }
            float mx = att[0];
#pragma unroll
            for (int h = 1; h < HHEADS; ++h) mx = fmaxf(mx, att[h]);
            float e[5], sum = 0.f;
#pragma unroll
            for (int h = 0; h < HHEADS; ++h) { e[h] = __expf(att[h] - mx); sum += e[h]; }
            float inv = 1.f / sum;
            if (lane < 32) {
#pragma unroll
                for (int h = 0; h < HHEADS; ++h) pf_s[mm * HHEADS + h] = e[h] * inv;
            }
        }

        // ---- aggregate: out[n, h*20+o] = sum_k pf[h*32+k] * t[k][o]  (reshape-faithful) ----
#pragma unroll
        for (int pass = 0; pass < 2; ++pass) {
            int idx = pass * 64 + lane;
            if (idx < HHEADS * OUTU) {
                int h = idx / OUTU, o = idx % OUTU;
                float s = 0.f;
#pragma unroll
                for (int kk = 0; kk < 8; ++kk) {
                    float4 p4 = *(const float4*)&pf_s[h * 32 + kk * 4];
                    float4 t4 = *(const float4*)&tT_s[o * 36 + kk * 4];
                    s += p4.x * t4.x + p4.y * t4.y + p4.z * t4.z + p4.w * t4.w;
                }
                out[(size_t)node * OUTW + idx] = s;
            }
        }
        // no barrier: per-wave LDS regions, same-wave RAW via lgkmcnt
    }
}

extern "C" void kernel_launch(void* const* d_in, const int* in_sizes, int n_in,
                              void* d_out, int out_size, void* d_ws, size_t ws_size,
                              hipStream_t stream) {
    const float* emb      = (const float*)d_in[0];
    const int*   node_idx = (const int*)d_in[1];
    const int*   neigh_idx= (const int*)d_in[2];
    const float* W1       = (const float*)d_in[3];
    const float* b1       = (const float*)d_in[4];
    const float* W2       = (const float*)d_in[5];
    const float* b2       = (const float*)d_in[6];
    const float* Wa       = (const float*)d_in[7];
    const float* ba       = (const float*)d_in[8];
    float* out = (float*)d_out;

    int ntot = in_sizes[0] / DEMB;                          // 200000
    int n    = in_sizes[1];                                 // 20000

    // ws layout
    unsigned short* W1fN = (unsigned short*)d_ws;                        // 28672 B
    unsigned short* W1fM = W1fN + 14336;                                 // 28672 B
    unsigned short* W2f  = W1fM + 14336;                                 //  8192 B
    unsigned short* hproj = (unsigned short*)((char*)d_ws + 65536);      // ntot*128*2
    float* nproj = (float*)((char*)d_ws + 65536 + (size_t)ntot * 256);   // n*128*4

    sa_prep<<<128, 256, 0, stream>>>(W1, W2, W1fN, W1fM, W2f);
    sa_hproj<<<(ntot + 127) / 128, 256, 0, stream>>>(emb, W1fN, hproj, ntot);
    sa_nproj<<<(n + 127) / 128, 256, 0, stream>>>(emb, node_idx, b1, W1fM, nproj, n);
    sa_main<<<(n + 4 * NITER - 1) / (4 * NITER), 256, 0, stream>>>(
        emb, node_idx, neigh_idx, b2, Wa, ba, hproj, nproj, W2f, out, n);
}